// Round 5
// baseline (233.175 us; speedup 1.0000x reference)
//
#include <hip/hip_runtime.h>
#include <stdint.h>
#include <math.h>

// BSRBF-KAN layer, FUSED, 2-blocks/CU (round 5):
// out = relu(LN(x)) @ base_W^T + (bspline+rbf)(LN(x)) @ spline_W^T
// K = 512 (relu region, A0 via global_load_lds) + 4096 (basis, computed into LDS).
// Round-5 change vs round-4: the CU previously hosted ONE 128KB-LDS block ->
// every barrier drained the whole CU (MfmaUtil 26 + VALU 34, ~40% idle).
// Now BM=128 x BN=128, BK=64, 4 waves, A/B double-buffered = 64.2 KB LDS,
// grid 512 -> TWO independent blocks per CU; one block's barrier/vmcnt drain
// overlaps the other's MFMA+VALU (m114 co-scheduling).  LDS is chunk-major
// [chunk(8)][row(128)][16B]: 8 consecutive lanes hit 8 consecutive 16B units
// -> conflict-free without XOR swizzle, and frag offsets are compile-time.
// Per-thread basis: 4 evals/tile (slots = 8 chunks x 128 rows / 256 thr),
// xn fetched as one 8B load (4 consecutive d per thread).  B prefetch
// depth-1 (drain covered by sibling block); xn prefetch depth-2.
//   ws: [W: 512*4608 f16][XN: 16384*512 f16][A0: 16384*512 f16]

#define D_IN  512
#define D_OUT 512
#define NB    8
#define KTOT  (D_IN + D_IN * NB)   // 4608
#define ROWS  16384
#define NT    (KTOT / 64)          // 72

typedef __attribute__((ext_vector_type(2))) _Float16 f16x2;
typedef __attribute__((ext_vector_type(8))) _Float16 f16x8;
typedef __attribute__((ext_vector_type(4))) float f32x4;

__device__ __forceinline__ float h2f(unsigned short u) {
  return (float)__builtin_bit_cast(_Float16, u);
}
__device__ __forceinline__ short f2h(float f) {
  return (short)__builtin_bit_cast(unsigned short, (_Float16)f);  // RNE
}
__device__ __forceinline__ unsigned pkrtz_u(float a, float b) {
  return __builtin_bit_cast(unsigned, __builtin_amdgcn_cvt_pkrtz(a, b));
}
__device__ __forceinline__ unsigned pkadd_f16(unsigned a, unsigned b) {
  f16x2 x = __builtin_bit_cast(f16x2, a), y = __builtin_bit_cast(f16x2, b);
  f16x2 r = x + y;
  return __builtin_bit_cast(unsigned, r);
}

// ---------------- prep: weight interleave + LayerNorm, one launch --------
__global__ __launch_bounds__(256) void prep_kernel(
    const float* __restrict__ x, const float* __restrict__ gamma,
    const float* __restrict__ beta, const float* __restrict__ bw,
    const float* __restrict__ sw, short* __restrict__ XN,
    short* __restrict__ A0, short* __restrict__ W) {
  if (blockIdx.x >= ROWS / 4) {
    const int o = blockIdx.x - ROWS / 4;
    for (int k = threadIdx.x; k < KTOT; k += 256) {
      const float v = (k < D_IN) ? bw[o * D_IN + k]
                                 : sw[(size_t)o * (D_IN * NB) + (k - D_IN)];
      W[(size_t)o * KTOT + k] = f2h(v);
    }
    return;
  }
  const int tid = threadIdx.x;
  const int lane = tid & 63, wave = tid >> 6;
  const int row = blockIdx.x * 4 + wave;
  const float* xr = x + (size_t)row * D_IN + lane * 8;

  const float4 a = *(const float4*)(xr);
  const float4 b = *(const float4*)(xr + 4);
  float xv[8] = {a.x, a.y, a.z, a.w, b.x, b.y, b.z, b.w};
  float s = 0.0f, ss = 0.0f;
#pragma unroll
  for (int e = 0; e < 8; e++) { s += xv[e]; ss += xv[e] * xv[e]; }
#pragma unroll
  for (int off = 32; off > 0; off >>= 1) {
    s += __shfl_xor(s, off);
    ss += __shfl_xor(ss, off);
  }
  const float mu = s * (1.0f / D_IN);
  const float var = ss * (1.0f / D_IN) - mu * mu;
  const float rstd = 1.0f / sqrtf(var + 1e-5f);

  const float4 g0 = *(const float4*)(gamma + lane * 8);
  const float4 g1 = *(const float4*)(gamma + lane * 8 + 4);
  const float4 b0 = *(const float4*)(beta + lane * 8);
  const float4 b1 = *(const float4*)(beta + lane * 8 + 4);
  float gv[8] = {g0.x, g0.y, g0.z, g0.w, g1.x, g1.y, g1.z, g1.w};
  float bv[8] = {b0.x, b0.y, b0.z, b0.w, b1.x, b1.y, b1.z, b1.w};

  unsigned xp[4], rp[4];
#pragma unroll
  for (int h = 0; h < 4; h++) {
    const float n0 = (xv[2 * h] - mu) * rstd * gv[2 * h] + bv[2 * h];
    const float n1 = (xv[2 * h + 1] - mu) * rstd * gv[2 * h + 1] + bv[2 * h + 1];
    const unsigned h0 = (unsigned)(unsigned short)f2h(n0);
    const unsigned h1 = (unsigned)(unsigned short)f2h(n1);
    xp[h] = h0 | (h1 << 16);
    rp[h] = (unsigned)(unsigned short)f2h(fmaxf(n0, 0.0f)) |
            ((unsigned)(unsigned short)f2h(fmaxf(n1, 0.0f)) << 16);
  }
  const uint4 xq = {xp[0], xp[1], xp[2], xp[3]};
  const uint4 rq = {rp[0], rp[1], rp[2], rp[3]};
  *(uint4*)&XN[(size_t)row * D_IN + lane * 8] = xq;
  *(uint4*)&A0[(size_t)row * D_IN + lane * 8] = rq;
}

// ---------------- basis eval: one d -> 8 packed f16 (spline + rbf) -------
// (verified in rounds 3/4) Spline via 14-entry perm-selector LUT; RBF via
// 3-transcendental cascade, z clamped to [-8,16].
__device__ __forceinline__ void basis_write(float xn, const uint4* lut,
                                            short* dst) {
  const float u = fmaf(xn, 1.66666667f, 5.5f);  // (xn+3.3)/0.6
  const float cf = floorf(u);
  const int c = (int)cf;
  const float t = u - cf;
  const float t2 = t * t, t3 = t2 * t, omt = 1.0f - t;
  const float v0 = t3 * 0.16666667f;
  const float v1 = fmaf(fmaf(fmaf(t, -0.5f, 0.5f), t, 0.5f), t, 0.16666667f);
  const float v2 = fmaf(t3, 0.5f, fmaf(t2, -1.0f, 0.66666667f));
  const float v3 = omt * omt * (omt * 0.16666667f);
  const unsigned va = pkrtz_u(v0, v1);
  const unsigned vb = pkrtz_u(v2, v3);

  float z = fmaf(xn, 2.80261895f, 4.20392842f);
  z = fminf(fmaxf(z, -8.0f), 16.0f);
  const float d3 = z - 3.60336723f;              // 3*DLT
  const float R3 = __builtin_amdgcn_exp2f(-(d3 * d3));
  const float G  = __builtin_amdgcn_exp2f(z * 2.40224482f);  // 2*DLT
  const float Gi = __builtin_amdgcn_rcpf(G);
  const float R4 = R3 * (G * 9.11881966e-4f);    // e^-7
  const float R5 = R4 * (G * 1.23409804e-4f);    // e^-9
  const float R6 = R5 * (G * 1.67017007e-5f);    // e^-11
  const float R7 = R6 * (G * 2.26032941e-6f);    // e^-13
  const float R2 = R3 * (Gi * 148.413159f);      // e^5
  const float R1 = R2 * (Gi * 20.0855369f);      // e^3
  const float R0 = R1 * (Gi * 2.71828183f);      // e^1

  const int idx = (c < -1 ? -1 : (c > 12 ? 12 : c)) + 1;
  const uint4 sel = lut[idx];
  const unsigned w0 = pkadd_f16(__builtin_amdgcn_perm(vb, va, sel.x), pkrtz_u(R0, R1));
  const unsigned w1 = pkadd_f16(__builtin_amdgcn_perm(vb, va, sel.y), pkrtz_u(R2, R3));
  const unsigned w2 = pkadd_f16(__builtin_amdgcn_perm(vb, va, sel.z), pkrtz_u(R4, R5));
  const unsigned w3 = pkadd_f16(__builtin_amdgcn_perm(vb, va, sel.w), pkrtz_u(R6, R7));
  const uint4 v4 = {w0, w1, w2, w3};
  *(uint4*)dst = v4;  // ds_write_b128
}

// ---------------- fused f16 MFMA GEMM, 2 blocks/CU -----------------------
#define GLL(g, l)                                               \
  __builtin_amdgcn_global_load_lds(                             \
      (const __attribute__((address_space(1))) void*)(g),       \
      (__attribute__((address_space(3))) void*)(l), 16, 0, 0)

__global__ __launch_bounds__(256, 2) void gemm_kernel(
    const short* __restrict__ A0, const short* __restrict__ XN,
    const short* __restrict__ W, float* __restrict__ out) {
  // chunk-major: buffer[chunk(8)][row(128)][8 shorts], 8 KB... x2 = 16 KB/tile
  __shared__ short As[2 * 8192];  // 32 KB (double-buffered A)
  __shared__ short Bs[2 * 8192];  // 32 KB (double-buffered B)
  __shared__ uint4 LUT[14];
  const int tid = threadIdx.x;               // 256
  const int lane = tid & 63, wave = tid >> 6;  // 4 waves

  // perm-selector LUT: entry idx = c+1, c clamped to [-1,12]
  if (tid < 14) {
    const int cc = tid - 1;
    unsigned e[4];
#pragma unroll
    for (int h = 0; h < 4; ++h) {
      const int m = cc - 2 * h, m2 = m - 1;
      const unsigned lo =
          (m >= 0 && m <= 3) ? (unsigned)((2 * m) | ((2 * m + 1) << 8)) : 0x0C0Cu;
      const unsigned hi =
          (m2 >= 0 && m2 <= 3) ? (unsigned)((2 * m2) | ((2 * m2 + 1) << 8)) : 0x0C0Cu;
      e[h] = lo | (hi << 16);
    }
    const uint4 ev = {e[0], e[1], e[2], e[3]};
    LUT[tid] = ev;
  }

  const int f = blockIdx.x;          // 512 blocks; f&3 n-minor: 4 blocks share A m-tile
  const int m0 = (f >> 2) * 128;
  const int n0 = (f & 3) * 128;
  const int wm = wave & 1, wn = wave >> 1;   // per-wave 64x64 output

  const f32x4 zero = {0.0f, 0.0f, 0.0f, 0.0f};
  f32x4 acc[4][4];
#pragma unroll
  for (int i = 0; i < 4; i++)
#pragma unroll
    for (int j = 0; j < 4; j++) acc[i][j] = zero;

  // staging: 16 GLL-instrs per tile (j = wave*4+i): chunk=j>>1, row=(j&1)*64+lane
  const short* pA[4];
  const short* pB[4];
#pragma unroll
  for (int i = 0; i < 4; i++) {
    const int j = wave * 4 + i;
    const int chunk = j >> 1;
    const int row = (j & 1) * 64 + lane;
    pA[i] = A0 + (size_t)(m0 + row) * D_IN + chunk * 8;
    pB[i] = W + (size_t)(n0 + row) * KTOT + chunk * 8;
  }

  // basis mapping: thread -> row = tid&127, chunks 4b..4b+3 (b = tid>>7);
  // d = (kt_next-512)/8 + chunk; 4 consecutive d -> one 8B xn load.
  const int brow = tid & 127, bsel = tid >> 7;
  const unsigned short* gX =
      (const unsigned short*)XN + (size_t)(m0 + brow) * D_IN + bsel * 4;
  const int bas0 = bsel * 4096 + brow * 8;   // + e*1024 per chunk

  const int lr = lane & 15;
  const int q = lane >> 4;
  const int aofs = q * 1024 + (wm * 64 + lr) * 8;  // + kk2*4096 + mi*128
  const int bofs = q * 1024 + (wn * 64 + lr) * 8;  // + kk2*4096 + nj*128

  short* Acur = As;        short* Anxt = As + 8192;
  short* Bcur = Bs;        short* Bnxt = Bs + 8192;

  // prologue: stage tile 0 into cur buffers
#pragma unroll
  for (int i = 0; i < 4; i++) {
    GLL(pA[i], Acur + (wave * 4 + i) * 512);
    GLL(pB[i], Bcur + (wave * 4 + i) * 512);
  }
  asm volatile("s_waitcnt vmcnt(0) lgkmcnt(0)" ::: "memory");
  __builtin_amdgcn_s_barrier();
  __builtin_amdgcn_sched_barrier(0);

  f16x8 af[2][4], bf[2][4];
#define READ_FRAGS(bufA, bufB)                                                 \
  do {                                                                         \
    _Pragma("unroll")                                                          \
    for (int kk2 = 0; kk2 < 2; kk2++) {                                        \
      _Pragma("unroll")                                                        \
      for (int mi = 0; mi < 4; mi++)                                           \
        af[kk2][mi] = *(const f16x8*)&(bufA)[aofs + kk2 * 4096 + mi * 128];    \
      _Pragma("unroll")                                                        \
      for (int nj = 0; nj < 4; nj++)                                           \
        bf[kk2][nj] = *(const f16x8*)&(bufB)[bofs + kk2 * 4096 + nj * 128];    \
    }                                                                          \
  } while (0)

  READ_FRAGS(Acur, Bcur);

  uint2 ca = {0u, 0u}, pa = {0u, 0u};  // xn quads for tiles t+1 / t+2

  for (int t = 0; t < NT; ++t) {
    const int tp1 = t + 1;
    // ---- stage next tile ----
    if (tp1 < NT) {
      if (tp1 < 8) {  // relu region: A via GLL
#pragma unroll
        for (int i = 0; i < 4; i++)
          GLL(pA[i] + tp1 * 64, Anxt + (wave * 4 + i) * 512);
      }
#pragma unroll
      for (int i = 0; i < 4; i++)
        GLL(pB[i] + tp1 * 64, Bnxt + (wave * 4 + i) * 512);
    }
    __builtin_amdgcn_sched_barrier(0);  // pin GLL-before-xn issue order
    if (t >= 6 && t <= NT - 3) {        // xn(t+2): newest VMEM, kept in flight
      pa = *(const uint2*)(gX + (size_t)(t + 2) * 8 - 64);
    }
    __builtin_amdgcn_sched_barrier(0);
    if (tp1 >= 8 && tp1 < NT) {  // basis region: compute A(t+1) into Anxt
      basis_write(h2f((unsigned short)(ca.x & 0xffffu)), LUT, Anxt + bas0);
      basis_write(h2f((unsigned short)(ca.x >> 16)),     LUT, Anxt + bas0 + 1024);
      basis_write(h2f((unsigned short)(ca.y & 0xffffu)), LUT, Anxt + bas0 + 2048);
      basis_write(h2f((unsigned short)(ca.y >> 16)),     LUT, Anxt + bas0 + 3072);
    }

    // ---- MFMA on current tile (operands in regs) ----
    __builtin_amdgcn_s_setprio(1);
#pragma unroll
    for (int kk2 = 0; kk2 < 2; kk2++)
#pragma unroll
      for (int mi = 0; mi < 4; mi++)
#pragma unroll
        for (int nj = 0; nj < 4; nj++)
          acc[mi][nj] = __builtin_amdgcn_mfma_f32_16x16x32_f16(
              af[kk2][mi], bf[kk2][nj], acc[mi][nj], 0, 0, 0);
    __builtin_amdgcn_s_setprio(0);

    if (tp1 < NT) {
      // drain staging (keep only the xn prefetch); publish ds_writes
      if (t >= 6 && t <= NT - 3) {
        asm volatile("s_waitcnt vmcnt(1) lgkmcnt(0)" ::: "memory");
      } else {
        asm volatile("s_waitcnt vmcnt(0) lgkmcnt(0)" ::: "memory");
      }
      __builtin_amdgcn_s_barrier();
      __builtin_amdgcn_sched_barrier(0);
      READ_FRAGS(Anxt, Bnxt);
      short* tA = Acur; Acur = Anxt; Anxt = tA;
      short* tB = Bcur; Bcur = Bnxt; Bnxt = tB;
    }
    ca = pa;
  }
#undef READ_FRAGS

  // C/D layout (m89-verified): col = lane&15, row = (lane>>4)*4 + reg
#pragma unroll
  for (int mi = 0; mi < 4; mi++) {
#pragma unroll
    for (int nj = 0; nj < 4; nj++) {
      const int gcol = n0 + wn * 64 + nj * 16 + lr;
#pragma unroll
      for (int r = 0; r < 4; r++) {
        const int grow = m0 + wm * 64 + mi * 16 + q * 4 + r;
        out[(size_t)grow * D_OUT + gcol] = acc[mi][nj][r];
      }
    }
  }
}

extern "C" void kernel_launch(void* const* d_in, const int* in_sizes, int n_in,
                              void* d_out, int out_size, void* d_ws, size_t ws_size,
                              hipStream_t stream) {
  const float* x     = (const float*)d_in[0];
  const float* gamma = (const float*)d_in[1];
  const float* beta  = (const float*)d_in[2];
  const float* bw    = (const float*)d_in[3];
  const float* sw    = (const float*)d_in[4];
  float* out = (float*)d_out;

  short* W  = (short*)d_ws;                          // 512 * 4608 f16
  short* XN = W + (size_t)D_OUT * KTOT;              // 16384 * 512 f16
  short* A0 = XN + (size_t)ROWS * D_IN;              // 16384 * 512 f16

  prep_kernel<<<ROWS / 4 + D_OUT, 256, 0, stream>>>(x, gamma, beta, bw, sw,
                                                    XN, A0, W);
  gemm_kernel<<<512, 256, 0, stream>>>(A0, XN, W, out);
}